// Round 1
// baseline (326.165 us; speedup 1.0000x reference)
//
#include <hip/hip_runtime.h>

// Problem constants (from reference)
#define B_      8
#define C_OUT_  64
#define GROUPS_ 4
#define NK_     7
#define C_IN_   1792          // GROUPS_ * C_OUT_ * NK_
#define L_      4096
#define NCH     28            // GROUPS_ * NK_ channels feeding one c_out

// Tiling
#define T_TILE  512
#define HALO    16            // shifts are in [-15, 15]
#define ROW     (T_TILE + 2 * HALO)     // 544 floats per staged channel row
#define GPR     (ROW / 4)               // 136 float4 granules per row
#define NGRAN   (NCH * GPR)             // 3808 granules of real data
#define NIT     15                      // ceil(3808 / 256)
#define NGRAN_P (NIT * 256)             // 3840 granules incl. pad
#define NTILE   (L_ / T_TILE)           // 8 tiles along L

// shift = REAL_PAD[idx % 7] = 15 - 5*m  ->  LDS idx = p + 1 + 5m (p = local t)

__device__ __forceinline__ void gload_lds16(const float* g, float* l) {
    // async global->LDS, 16B/lane; LDS dest is wave-uniform base + lane*16
    __builtin_amdgcn_global_load_lds(
        (const __attribute__((address_space(1))) void*)g,
        (__attribute__((address_space(3))) void*)l,
        16, 0, 0);
}

__global__ __launch_bounds__(256, 2)
void addshift_fused_kernel(const float* __restrict__ x,
                           const int*   __restrict__ s1,
                           const int*   __restrict__ s2,
                           const int*   __restrict__ s3,
                           float*       __restrict__ out)
{
    __shared__ __align__(16) float lx[NGRAN_P * 4];   // 61440 B -> 2 blocks/CU

    const int tid  = threadIdx.x;
    const int blk  = blockIdx.x;
    const int tile = blk & (NTILE - 1);          // 8 tiles along L
    const int co   = (blk >> 3) & (C_OUT_ - 1);
    const int b    = blk >> 9;                   // 8 batches
    const int t0   = tile * T_TILE;

    const int base_b = b * (C_IN_ * L_);         // max ~58.7M incl ch, fits int
    const int wbase  = tid & ~63;                // wave start within block

    // ---- Stage 28 channel rows straight into LDS (no VGPR round-trip) ----
    // Linear LDS layout: granule gi -> floats [gi*4, gi*4+4); lanes of a wave
    // write consecutive granules, matching global_load_lds's base+lane*16.
#pragma unroll
    for (int it = 0; it < NIT; ++it) {
        const int gi  = it * 256 + tid;                      // 0..3839
        const int gic = gi > (NGRAN - 1) ? (NGRAN - 1) : gi; // clamp tail -> valid addr
        const int cl  = gic / GPR;                           // 0..27 (magic div)
        const int j   = gic - cl * GPR;                      // 0..135
        const int g   = cl / NK_;
        const int k   = cl - g * NK_;
        const int ch  = g * (C_OUT_ * NK_) + co * NK_ + k;
        const int e   = t0 - HALO + j * 4;                   // multiple of 4
        // granule is always fully inside or fully outside [0, L)
        const int ec  = e < 0 ? 0 : (e > L_ - 4 ? L_ - 4 : e);
        gload_lds16(x + base_b + ch * L_ + ec, &lx[(it * 256 + wbase) * 4]);
    }
    __syncthreads();   // drains vmcnt(0) before barrier (compiler-enforced)

    // ---- Zero-fix OOB halo granules (only tiles 0 and NTILE-1) ----
    if (tile == 0 || tile == NTILE - 1) {
#pragma unroll
        for (int it = 0; it < NIT; ++it) {
            const int gi = it * 256 + tid;
            if (gi < NGRAN) {
                const int cl = gi / GPR;
                const int j  = gi - cl * GPR;
                const int e  = t0 - HALO + j * 4;
                if (e < 0 || e > L_ - 4)
                    *(float4*)&lx[gi * 4] = make_float4(0.f, 0.f, 0.f, 0.f);
            }
        }
        __syncthreads();
    }

    // ---- Accumulate 3 outputs, 2 consecutive t per thread ----
    // shifts are block-uniform (s_load + SALU magic-div); per (cl,set):
    // 1 v_add (addr) + 1 ds_read2_b32 + 2 v_add_f32 for TWO output elements.
    float a1 = 0.f, c1 = 0.f, a2 = 0.f, c2 = 0.f, a3 = 0.f, c3 = 0.f;
    const int p = 2 * tid;                       // local t offset 0..510
#pragma unroll
    for (int g = 0; g < GROUPS_; ++g) {
#pragma unroll
        for (int k = 0; k < NK_; ++k) {
            const int cl = g * NK_ + k;
            const int ch = g * (C_OUT_ * NK_) + co * NK_ + k;
            const int m1 = s1[ch] % NK_;         // uniform -> SALU
            const int m2 = s2[ch] % NK_;
            const int m3 = s3[ch] % NK_;
            const float* r = &lx[cl * ROW + p + 1];
            const float* r1 = r + 5 * m1;  a1 += r1[0];  c1 += r1[1];
            const float* r2 = r + 5 * m2;  a2 += r2[0];  c2 += r2[1];
            const float* r3 = r + 5 * m3;  a3 += r3[0];  c3 += r3[1];
        }
    }

    const int opos = (b * C_OUT_ + co) * L_ + t0 + p;    // 8B-aligned (p even)
    *(float2*)&out[opos]                        = make_float2(a1, c1);
    *(float2*)&out[B_ * C_OUT_ * L_ + opos]     = make_float2(a2, c2);
    *(float2*)&out[2 * B_ * C_OUT_ * L_ + opos] = make_float2(a3, c3);
}

extern "C" void kernel_launch(void* const* d_in, const int* in_sizes, int n_in,
                              void* d_out, int out_size, void* d_ws, size_t ws_size,
                              hipStream_t stream) {
    const float* x  = (const float*)d_in[0];
    const int*   s1 = (const int*)d_in[1];
    const int*   s2 = (const int*)d_in[2];
    const int*   s3 = (const int*)d_in[3];
    float* out = (float*)d_out;

    const int n_blocks = B_ * C_OUT_ * NTILE;   // 4096
    addshift_fused_kernel<<<dim3(n_blocks), dim3(256), 0, stream>>>(x, s1, s2, s3, out);
}